// Round 4
// baseline (377.113 us; speedup 1.0000x reference)
//
#include <hip/hip_runtime.h>
#include <math.h>
#include <stdint.h>

#define LSEQ 8192
#define DIN  512
#define NB   8
#define NO   1024
#define NK2  256

typedef __bf16 bf16x8 __attribute__((ext_vector_type(8)));
typedef float f32x16 __attribute__((ext_vector_type(16)));

__device__ __forceinline__ uint32_t pack_bf16_rne(float lo, float hi) {
    uint32_t ul = __builtin_bit_cast(uint32_t, lo);
    uint32_t uh = __builtin_bit_cast(uint32_t, hi);
    ul += 0x7FFFu + ((ul >> 16) & 1u);
    uh += 0x7FFFu + ((uh >> 16) & 1u);
    return (ul >> 16) | (uh & 0xFFFF0000u);
}
__device__ __forceinline__ float bf16_lo(uint32_t w) {
    return __builtin_bit_cast(float, w << 16);
}
__device__ __forceinline__ float bf16_hi(uint32_t w) {
    return __builtin_bit_cast(float, w & 0xFFFF0000u);
}
__device__ __forceinline__ void load_lds_16B(const uint32_t* g, uint32_t* l) {
    __builtin_amdgcn_global_load_lds(
        (const __attribute__((address_space(1))) void*)g,
        (__attribute__((address_space(3))) void*)l, 16, 0, 0);
}

// ---------------- Kernel 1: weight norm -> bf16 ----------------
__global__ void norm_kernel(const float* __restrict__ W, uint32_t* __restrict__ Wnb) {
    const int o = blockIdx.x;
    const int lane = threadIdx.x;  // 0..63
    const float* row = W + (size_t)o * DIN;
    float4 v0 = *(const float4*)(row + lane * 4);
    float4 v1 = *(const float4*)(row + 256 + lane * 4);
    float s = v0.x * v0.x + v0.y * v0.y + v0.z * v0.z + v0.w * v0.w
            + v1.x * v1.x + v1.y * v1.y + v1.z * v1.z + v1.w * v1.w;
#pragma unroll
    for (int m = 32; m; m >>= 1) s += __shfl_xor(s, m, 64);
    const float sq = 22.62741699796952f;  // sqrt(512)
    const float scale = 1.0f / ((1e-4f + sqrtf(s) / sq) * sq);
    uint2 w0, w1;
    w0.x = pack_bf16_rne(v0.x * scale, v0.y * scale);
    w0.y = pack_bf16_rne(v0.z * scale, v0.w * scale);
    w1.x = pack_bf16_rne(v1.x * scale, v1.y * scale);
    w1.y = pack_bf16_rne(v1.z * scale, v1.w * scale);
    *(uint2*)&Wnb[o * 256 + lane * 2] = w0;
    *(uint2*)&Wnb[o * 256 + 128 + lane * 2] = w1;
}

// ---------------- Kernel 1b: pack x -> bf16 k2-interleaved ----------------
// xi word (b, k2, l) = bf16 x[b][2k2][l] | bf16 x[b][2k2+1][l] << 16
__global__ __launch_bounds__(256)
void pack_kernel(const float* __restrict__ x, uint32_t* __restrict__ xi) {
    const int k2 = blockIdx.x;
    const int b  = blockIdx.y;
    const float* r0 = x + ((size_t)b * DIN + 2 * k2) * LSEQ;
    const float* r1 = r0 + LSEQ;
    uint32_t* orow = xi + ((size_t)b * NK2 + k2) * LSEQ;
#pragma unroll
    for (int i = 0; i < 8; ++i) {
        const int idx = i * 1024 + threadIdx.x * 4;
        float4 a = *(const float4*)(r0 + idx);
        float4 c = *(const float4*)(r1 + idx);
        uint4 w;
        w.x = pack_bf16_rne(a.x, c.x);
        w.y = pack_bf16_rne(a.y, c.y);
        w.z = pack_bf16_rne(a.z, c.z);
        w.w = pack_bf16_rne(a.w, c.w);
        *(uint4*)(orow + idx) = w;
    }
}

// ---------------- Kernel 2: bf16 MFMA GEMM ----------------
// B staged via global_load_lds (direct HBM/L2 -> LDS DMA, no VALU repack).
// LDS B: 16 k2-rows x 128 words, pitch 128 (frag reads are 2-way = free).
__global__ __launch_bounds__(256)
void gemm_kernel(const uint16_t* __restrict__ Wnb, const uint32_t* __restrict__ xi,
                 uint32_t* __restrict__ fbp) {
    __shared__ uint32_t sA[2048];  // 8 KB, XOR-swizzled granules
    __shared__ uint32_t sB[2048];  // 8 KB, [k2][l] pitch 128

    const int tid  = threadIdx.x;
    const int lane = tid & 63;
    const int w    = tid >> 6;
    const int wm   = w & 1, wn = w >> 1;

    const int bx  = blockIdx.x;
    const int xcd = bx & 7;
    const int t   = bx >> 3;
    const int o0  = (t & 7) * 128;
    const int l0  = (xcd + ((t >> 3) << 3)) * 128;
    const int b   = blockIdx.y;

    const uint32_t* xib = xi + (size_t)b * NK2 * LSEQ + l0;

    // A staging (bf16 weights, direct copy + swizzle)
    const int am = tid >> 1;
    const int aq = (tid & 1) * 2;
    const uint16_t* arow = Wnb + (size_t)(o0 + am) * DIN + aq * 8;
    const uint32_t aw0 = am * 16 + ((aq ^ (am & 3)) * 4);
    const uint32_t aw1 = am * 16 + (((aq + 1) ^ (am & 3)) * 4);

    // B DMA addressing: wave w, instr j covers k2-rows (w*4 + j*2) + (lane>>5)
    const int rA = w * 4 + (lane >> 5);      // j=0 row
    const int rB = w * 4 + 2 + (lane >> 5);  // j=1 row
    const int lw = (lane & 31) * 4;

    f32x16 acc[2][2];
#pragma unroll
    for (int i = 0; i < 2; ++i)
#pragma unroll
        for (int j = 0; j < 2; ++j)
#pragma unroll
            for (int r = 0; r < 16; ++r) acc[i][j][r] = 0.f;

    uint4 aR0 = *(const uint4*)(arow);
    uint4 aR1 = *(const uint4*)(arow + 8);

#pragma unroll 1
    for (int it = 0; it < 16; ++it) {
        __syncthreads();
        *(uint4*)&sA[aw0] = aR0;
        *(uint4*)&sA[aw1] = aR1;
        {
            const uint32_t* gb = xib + (size_t)(it * 16) * LSEQ;
            load_lds_16B(gb + (size_t)rA * LSEQ + lw, &sB[(w * 4) * 128]);
            load_lds_16B(gb + (size_t)rB * LSEQ + lw, &sB[(w * 4 + 2) * 128]);
        }
        if (it + 1 < 16) {
            const int kt = (it + 1) * 32;
            aR0 = *(const uint4*)(arow + kt);
            aR1 = *(const uint4*)(arow + kt + 8);
        }
        __syncthreads();
#pragma unroll
        for (int kh = 0; kh < 2; ++kh) {
            bf16x8 af[2], bfr[2];
#pragma unroll
            for (int ms = 0; ms < 2; ++ms) {
                const int m = wm * 64 + ms * 32 + (lane & 31);
                const int q = kh * 2 + (lane >> 5);
                af[ms] = *(const bf16x8*)&sA[m * 16 + ((q ^ (m & 3)) * 4)];
            }
#pragma unroll
            for (int ns = 0; ns < 2; ++ns) {
                const int col = wn * 64 + ns * 32 + (lane & 31);
                const int rb = kh * 8 + (lane >> 5) * 4;
                uint4 tt;
                tt.x = sB[(rb + 0) * 128 + col];
                tt.y = sB[(rb + 1) * 128 + col];
                tt.z = sB[(rb + 2) * 128 + col];
                tt.w = sB[(rb + 3) * 128 + col];
                bfr[ns] = __builtin_bit_cast(bf16x8, tt);
            }
#pragma unroll
            for (int ms = 0; ms < 2; ++ms)
#pragma unroll
                for (int ns = 0; ns < 2; ++ns)
                    acc[ms][ns] = __builtin_amdgcn_mfma_f32_32x32x16_bf16(
                        af[ms], bfr[ns], acc[ms][ns], 0, 0, 0);
        }
    }

    // epilogue: pack adjacent-o pairs -> one uint32 word
    uint32_t* fbp_b = fbp + (size_t)b * 512 * LSEQ + l0;
#pragma unroll
    for (int ms = 0; ms < 2; ++ms)
#pragma unroll
        for (int ns = 0; ns < 2; ++ns) {
            const f32x16 a = acc[ms][ns];
            const int rb = o0 + wm * 64 + ms * 32 + 4 * (lane >> 5);  // even
            const int cc = wn * 64 + ns * 32 + (lane & 31);
#pragma unroll
            for (int rp = 0; rp < 8; ++rp) {
                const int r = rp * 2;
                const int row = rb + (r & 3) + 8 * (r >> 2);  // even
                fbp_b[(size_t)(row >> 1) * LSEQ + cc] = pack_bf16_rne(a[r], a[r + 1]);
            }
        }
}

// ---------------- Kernel 3: minGRU scan, direct strided loads/stores -------
// Thread t owns the contiguous 64B chunk l in [t*16, t*16+16) for 2 channels.
__global__ __launch_bounds__(512)
void scan_kernel(const uint32_t* __restrict__ fbp, float* __restrict__ out) {
    __shared__ float sA0[8], sB0[8], sA1[8], sB1[8];

    const int bx  = blockIdx.x;  // 0..255
    const int b   = blockIdx.y;
    const int dir = bx >> 7;
    const int p   = bx & 127;
    const int o2h = dir * 256 + p;
    const int o2g = o2h + 128;

    const int t    = threadIdx.x;
    const int lane = t & 63;
    const int w    = t >> 6;

    const uint4* hp = (const uint4*)(fbp + ((size_t)b * 512 + o2h) * LSEQ + t * 16);
    const uint4* gp = (const uint4*)(fbp + ((size_t)b * 512 + o2g) * LSEQ + t * 16);
    uint4 hw4[4], gw4[4];
#pragma unroll
    for (int i = 0; i < 4; ++i) hw4[i] = hp[i];
#pragma unroll
    for (int i = 0; i < 4; ++i) gw4[i] = gp[i];

    float av0[16], vv0[16], av1[16], vv1[16];
#pragma unroll
    for (int q = 0; q < 4; ++q) {
        const uint32_t hws[4] = {hw4[q].x, hw4[q].y, hw4[q].z, hw4[q].w};
        const uint32_t gws[4] = {gw4[q].x, gw4[q].y, gw4[q].z, gw4[q].w};
#pragma unroll
        for (int s = 0; s < 4; ++s) {
            const int mo = q * 4 + s;
            {
                float g_ = fminf(fmaxf(bf16_lo(gws[s]), -30.f), 30.f);
                float eg = __expf(g_);
                float a  = rsqrtf(fmaf(eg, eg, 1.f));
                float h_ = bf16_lo(hws[s]);
                av0[mo] = a;
                vv0[mo] = a * eg * copysignf(fmaxf(fabsf(h_), 1e-6f), h_);
            }
            {
                float g_ = fminf(fmaxf(bf16_hi(gws[s]), -30.f), 30.f);
                float eg = __expf(g_);
                float a  = rsqrtf(fmaf(eg, eg, 1.f));
                float h_ = bf16_hi(hws[s]);
                av1[mo] = a;
                vv1[mo] = a * eg * copysignf(fmaxf(fabsf(h_), 1e-6f), h_);
            }
        }
    }

    float A0 = 1.f, B0 = 0.f, A1 = 1.f, B1 = 0.f;
    if (dir == 0) {
#pragma unroll
        for (int i = 0; i < 16; ++i) {
            B0 = fmaf(av0[i], B0, vv0[i]); A0 *= av0[i];
            B1 = fmaf(av1[i], B1, vv1[i]); A1 *= av1[i];
        }
    } else {
#pragma unroll
        for (int i = 15; i >= 0; --i) {
            B0 = fmaf(av0[i], B0, vv0[i]); A0 *= av0[i];
            B1 = fmaf(av1[i], B1, vv1[i]); A1 *= av1[i];
        }
    }

    if (dir == 0) {
#pragma unroll
        for (int off = 1; off < 64; off <<= 1) {
            float Ap0 = __shfl_up(A0, (unsigned)off, 64), Bp0 = __shfl_up(B0, (unsigned)off, 64);
            float Ap1 = __shfl_up(A1, (unsigned)off, 64), Bp1 = __shfl_up(B1, (unsigned)off, 64);
            if (lane >= off) {
                B0 = fmaf(A0, Bp0, B0); A0 *= Ap0;
                B1 = fmaf(A1, Bp1, B1); A1 *= Ap1;
            }
        }
        if (lane == 63) { sA0[w] = A0; sB0[w] = B0; sA1[w] = A1; sB1[w] = B1; }
    } else {
#pragma unroll
        for (int off = 1; off < 64; off <<= 1) {
            float Ap0 = __shfl_down(A0, (unsigned)off, 64), Bp0 = __shfl_down(B0, (unsigned)off, 64);
            float Ap1 = __shfl_down(A1, (unsigned)off, 64), Bp1 = __shfl_down(B1, (unsigned)off, 64);
            if (lane + off < 64) {
                B0 = fmaf(A0, Bp0, B0); A0 *= Ap0;
                B1 = fmaf(A1, Bp1, B1); A1 *= Ap1;
            }
        }
        if (lane == 0) { sA0[w] = A0; sB0[w] = B0; sA1[w] = A1; sB1[w] = B1; }
    }
    __syncthreads();
    float WB0 = 0.f, WB1 = 0.f;
    if (dir == 0) {
        for (int wv = 0; wv < w; ++wv) {
            WB0 = fmaf(sA0[wv], WB0, sB0[wv]);
            WB1 = fmaf(sA1[wv], WB1, sB1[wv]);
        }
    } else {
        for (int wv = 7; wv > w; --wv) {
            WB0 = fmaf(sA0[wv], WB0, sB0[wv]);
            WB1 = fmaf(sA1[wv], WB1, sB1[wv]);
        }
    }
    float eA0, eB0, eA1, eB1;
    if (dir == 0) {
        eA0 = __shfl_up(A0, 1u, 64); eB0 = __shfl_up(B0, 1u, 64);
        eA1 = __shfl_up(A1, 1u, 64); eB1 = __shfl_up(B1, 1u, 64);
        if (lane == 0) { eA0 = 1.f; eB0 = 0.f; eA1 = 1.f; eB1 = 0.f; }
    } else {
        eA0 = __shfl_down(A0, 1u, 64); eB0 = __shfl_down(B0, 1u, 64);
        eA1 = __shfl_down(A1, 1u, 64); eB1 = __shfl_down(B1, 1u, 64);
        if (lane == 63) { eA0 = 1.f; eB0 = 0.f; eA1 = 1.f; eB1 = 0.f; }
    }
    float H0 = fmaf(eA0, WB0, eB0);
    float H1 = fmaf(eA1, WB1, eB1);

    if (dir == 0) {
#pragma unroll
        for (int i = 0; i < 16; ++i) {
            H0 = fmaf(av0[i], H0, vv0[i]); vv0[i] = H0;
            H1 = fmaf(av1[i], H1, vv1[i]); vv1[i] = H1;
        }
    } else {
#pragma unroll
        for (int i = 15; i >= 0; --i) {
            H0 = fmaf(av0[i], H0, vv0[i]); vv0[i] = H0;
            H1 = fmaf(av1[i], H1, vv1[i]); vv1[i] = H1;
        }
    }

    float* o0p = out + ((size_t)b * 512 + dir * 256 + 2 * p) * LSEQ + t * 16;
    float* o1p = o0p + LSEQ;
#pragma unroll
    for (int q = 0; q < 4; ++q) {
        *(float4*)(o0p + q * 4) =
            make_float4(vv0[q * 4], vv0[q * 4 + 1], vv0[q * 4 + 2], vv0[q * 4 + 3]);
        *(float4*)(o1p + q * 4) =
            make_float4(vv1[q * 4], vv1[q * 4 + 1], vv1[q * 4 + 2], vv1[q * 4 + 3]);
    }
}

// ---------------- launch ----------------
extern "C" void kernel_launch(void* const* d_in, const int* in_sizes, int n_in,
                              void* d_out, int out_size, void* d_ws, size_t ws_size,
                              hipStream_t stream) {
    const float* x = (const float*)d_in[0];  // (8, 512, 8192)
    const float* W = (const float*)d_in[1];  // (1024, 512, 1)
    float* out = (float*)d_out;              // (8, 512, 8192)

    uint32_t* Wnb = (uint32_t*)d_ws;                                  // 1 MB
    uint32_t* fbp = (uint32_t*)((char*)d_ws + (size_t)NO * DIN * 2);  // 134 MB
    uint32_t* xi  = (uint32_t*)d_out;  // 67 MB scratch in d_out (dead until scan)

    norm_kernel<<<dim3(NO), dim3(64), 0, stream>>>(W, Wnb);
    pack_kernel<<<dim3(NK2, NB), dim3(256), 0, stream>>>(x, xi);
    gemm_kernel<<<dim3(512, NB), dim3(256), 0, stream>>>((const uint16_t*)Wnb, xi, fbp);
    scan_kernel<<<dim3(256, NB), dim3(512), 0, stream>>>(fbp, out);
}